// Round 7
// baseline (1071.541 us; speedup 1.0000x reference)
//
#include <hip/hip_runtime.h>
#include <stdint.h>

#define NN 8192
#define IN_DIM 32
#define HID_DIM 64
#define OUT_DIM 16

typedef __attribute__((ext_vector_type(8))) short short8;
typedef __attribute__((ext_vector_type(4))) float f32x4;

// fp32 -> bf16 bits, round-to-nearest-even
__device__ __forceinline__ short f2bf_bits(float x){
  uint32_t u = __builtin_bit_cast(uint32_t, x);
  u += 0x7FFFu + ((u >> 16) & 1u);
  return (short)(u >> 16);
}

__device__ __forceinline__ short8 cvt8(f32x4 lo, f32x4 hi){
  short8 r;
  r[0]=f2bf_bits(lo[0]); r[1]=f2bf_bits(lo[1]); r[2]=f2bf_bits(lo[2]); r[3]=f2bf_bits(lo[3]);
  r[4]=f2bf_bits(hi[0]); r[5]=f2bf_bits(hi[1]); r[6]=f2bf_bits(hi[2]); r[7]=f2bf_bits(hi[3]);
  return r;
}

// Kernel 0: Gt[c][r] = bf16( (X @ W1)[r][c] )   [64][8192]
__global__ __launch_bounds__(256) void k_g(const float* __restrict__ X, const float* __restrict__ W1,
                                           short* __restrict__ Gt){
  const int b    = blockIdx.x;
  const int rb   = (b & 127) * 64;
  const int cg   = b >> 7;
  const int lane = threadIdx.x & 63;
  const int c    = cg * 4 + (threadIdx.x >> 6);
  const int r    = rb + lane;
  const float* xr = X + (size_t)r * IN_DIM;
  float acc = 0.f;
  #pragma unroll
  for (int k = 0; k < IN_DIM; ++k)
    acc += xr[k] * W1[(size_t)k * HID_DIM + c];
  Gt[(size_t)c * NN + r] = f2bf_bits(acc);
}

// mm_sw: single-wave blocks, NO __syncthreads -> no vmcnt(0) drains ever.
// Block = 64 threads = 1 wave, owns 16 rows of ONE adj matrix (blockIdx.z).
// K-group = 64 cols (4 KB staged via 4x global_load_lds, 256 B/row runs).
// 3-deep LDS ring (12 KB -> 13 blocks/CU). Pacing: constant asm vmcnt(16):
// in flight = stage(t+1),stage(t+2) [8 ops] + B(t+1) [8 ops]; B prefetched one
// group ahead and issued BEFORE stages so its consumption never drains younger
// staging ops (vmcnt retires in order, m135). Granule-XOR (g ^ row) applied at
// the GLOBAL source, LDS linear (m104/m173); read undoes it.
template<int REV>
__global__ __launch_bounds__(64, 4) void mm_sw(const float* __restrict__ adj1, const float* __restrict__ adj2,
                                               const short* __restrict__ Bt,
                                               float* __restrict__ P1, float* __restrict__ P2, int klen){
  __shared__ __align__(16) float sA[3][16 * 64];      // 12 KB ring
  const int l    = threadIdx.x;                       // 0..63
  const int strip= REV ? ((int)gridDim.x - 1 - (int)blockIdx.x) : (int)blockIdx.x;
  const int ks   = REV ? ((int)gridDim.y - 1 - (int)blockIdx.y) : (int)blockIdx.y;
  const float* __restrict__ adj = blockIdx.z ? adj2 : adj1;
  const int k0   = ks * klen;
  const int ngrp = klen >> 6;                         // 32 at S=4
  const int rl   = l & 15;                            // MFMA row / B col
  const int qh   = l >> 4;                            // k-quad
  const int sr4  = l >> 4;                            // stage row-in-quad
  const int sgr  = l & 15;                            // stage granule
  const size_t rowb = (size_t)strip * 16 * NN;

  auto stage = [&](int t){
    const int tg = t & (ngrp - 1);
    const int g  = REV ? (ngrp - 1 - tg) : tg;
    const int buf = t % 3;
    const size_t colb = (size_t)(k0 + g * 64);
    #pragma unroll
    for (int p = 0; p < 4; ++p){
      const int row = p * 4 + sr4;                    // 0..15
      const int sg  = sgr ^ row;                      // source granule (16B)
      const float* s = adj + rowb + (size_t)row * NN + colb + sg * 4;
      __builtin_amdgcn_global_load_lds(
          (const __attribute__((address_space(1))) void*)s,
          (__attribute__((address_space(3))) void*)&sA[buf][p * 256 + l * 4], 16, 0, 0);
    }
  };

  auto loadB = [&](int t, short8 bf[2][4]){
    const int tg = t & (ngrp - 1);
    const int g  = REV ? (ngrp - 1 - tg) : tg;
    const size_t bk = (size_t)(k0 + g * 64) + qh * 8;
    #pragma unroll
    for (int j = 0; j < 2; ++j)
      #pragma unroll
      for (int f = 0; f < 4; ++f)
        bf[j][f] = *(const short8*)(Bt + (size_t)(f * 16 + rl) * NN + bk + j * 32);
  };

  f32x4 acc[4] = {{0,0,0,0},{0,0,0,0},{0,0,0,0},{0,0,0,0}};
  short8 bf[2][2][4];

  // prologue: B(0) first (oldest), then stages 0,1
  loadB(0, bf[0]);
  stage(0); stage(1);

  #pragma unroll 2
  for (int t = 0; t < ngrp; ++t){
    loadB(t + 1, bf[(t + 1) & 1]);                    // issued BEFORE stage(t+2)
    stage(t + 2);                                     // ring wrap at tail: harmless
    // wait: all ops older than {stage(t+1),stage(t+2),B(t+1)} = 16 done
    asm volatile("s_waitcnt vmcnt(16)" ::: "memory");
    __builtin_amdgcn_sched_barrier(0);
    const float* sa = &sA[t % 3][0];
    #pragma unroll
    for (int j = 0; j < 2; ++j){
      const int g0 = j * 8 + qh * 2;
      f32x4 lo = *(const f32x4*)(sa + rl * 64 + (((g0    ) ^ rl) << 2));
      f32x4 hi = *(const f32x4*)(sa + rl * 64 + (((g0 + 1) ^ rl) << 2));
      short8 fa = cvt8(lo, hi);
      #pragma unroll
      for (int f = 0; f < 4; ++f)
        acc[f] = __builtin_amdgcn_mfma_f32_16x16x32_bf16(fa, bf[t & 1][j][f], acc[f], 0, 0, 0);
    }
  }

  // D layout: col = lane&15, row = (lane>>4)*4 + reg
  const int orow = strip * 16 + qh * 4;
  float* P = blockIdx.z ? P2 : P1;
  float* p = P + ((size_t)ks * NN + orow) * HID_DIM + rl;
  #pragma unroll
  for (int r = 0; r < 4; ++r){
    #pragma unroll
    for (int f = 0; f < 4; ++f)
      p[(size_t)r * HID_DIM + f * 16] = acc[f][r];
  }
}

// l1_combine: H1t[c][r] = bf16( relu(SY1+b1) + relu(SY2+b1) ), LDS transpose
__global__ __launch_bounds__(256) void l1_combine(const float* __restrict__ Y1p, const float* __restrict__ Y2p,
                                                  const float* __restrict__ b1,
                                                  short* __restrict__ H1t, int S){
  __shared__ float sH[64][65];
  const int tid = threadIdx.x, lane = tid & 63, wave = tid >> 6;
  const int rb = blockIdx.x * 64;
  const float bc = b1[lane];
  #pragma unroll 4
  for (int rq = 0; rq < 16; ++rq){
    const int r = rq * 4 + wave;
    const int row = rb + r;
    float s1 = 0.f, s2 = 0.f;
    for (int sp = 0; sp < S; ++sp){
      s1 += Y1p[((size_t)sp * NN + row) * HID_DIM + lane];
      s2 += Y2p[((size_t)sp * NN + row) * HID_DIM + lane];
    }
    sH[r][lane] = fmaxf(s1 + bc, 0.f) + fmaxf(s2 + bc, 0.f);
  }
  __syncthreads();
  #pragma unroll 4
  for (int i = 0; i < 16; ++i){
    const int c = wave * 16 + i;
    H1t[(size_t)c * NN + rb + lane] = f2bf_bits(sH[lane][c]);
  }
}

// l2_combine: out[row][c] = relu(Z1@W2+b2) + relu(Z2@W2+b2)
__global__ __launch_bounds__(256) void l2_combine(const float* __restrict__ Z1p, const float* __restrict__ Z2p,
                                                  const float* __restrict__ W2, const float* __restrict__ b2,
                                                  float* __restrict__ out, int S){
  __shared__ float sW[HID_DIM * OUT_DIM];
  __shared__ float sb[OUT_DIM];
  __shared__ float sz[4][2][HID_DIM];
  const int tid = threadIdx.x;
  for (int i = tid; i < HID_DIM * OUT_DIM; i += 256) sW[i] = W2[i];
  if (tid < OUT_DIM) sb[tid] = b2[tid];
  const int sub = tid >> 6, t = tid & 63;
  const int row = blockIdx.x * 4 + sub;
  float s1 = 0.f, s2 = 0.f;
  for (int sp = 0; sp < S; ++sp){
    s1 += Z1p[((size_t)sp * NN + row) * HID_DIM + t];
    s2 += Z2p[((size_t)sp * NN + row) * HID_DIM + t];
  }
  sz[sub][0][t] = s1;
  sz[sub][1][t] = s2;
  __syncthreads();
  if (t < OUT_DIM){
    float a = sb[t], b = sb[t];
    #pragma unroll
    for (int k = 0; k < HID_DIM; ++k){
      a += sz[sub][0][k] * sW[k * OUT_DIM + t];
      b += sz[sub][1][k] * sW[k * OUT_DIM + t];
    }
    out[(size_t)row * OUT_DIM + t] = fmaxf(a, 0.f) + fmaxf(b, 0.f);
  }
}

extern "C" void kernel_launch(void* const* d_in, const int* in_sizes, int n_in,
                              void* d_out, int out_size, void* d_ws, size_t ws_size,
                              hipStream_t stream){
  const float* adj1 = (const float*)d_in[0];
  const float* adj2 = (const float*)d_in[1];
  const float* X    = (const float*)d_in[2];
  const float* W1   = (const float*)d_in[3];
  const float* b1   = (const float*)d_in[4];
  const float* W2   = (const float*)d_in[5];
  const float* b2   = (const float*)d_in[6];
  float* out = (float*)d_out;

  char* ws = (char*)d_ws;
  short* Gt  = (short*)ws;                           // 64*8192*2 = 1 MB
  short* H1t = (short*)(ws + (size_t)1024 * 1024);   // 1 MB
  const size_t off = (size_t)2 * 1024 * 1024;

  int S = 4;
  while (S > 1 && off + (size_t)S * 4 * 1024 * 1024 > ws_size) S >>= 1;
  float* P1 = (float*)(ws + off);
  float* P2 = P1 + (size_t)S * NN * HID_DIM;
  const int klen = NN / S;

  k_g        <<<dim3(2048),             dim3(256), 0, stream>>>(X, W1, Gt);
  mm_sw<0>   <<<dim3(NN / 16, S, 2),    dim3(64),  0, stream>>>(adj1, adj2, Gt, P1, P2, klen);
  l1_combine <<<dim3(NN / 64),          dim3(256), 0, stream>>>(P1, P2, b1, H1t, S);
  mm_sw<1>   <<<dim3(NN / 16, S, 2),    dim3(64),  0, stream>>>(adj1, adj2, H1t, P1, P2, klen);
  l2_combine <<<dim3(NN / 4),           dim3(256), 0, stream>>>(P1, P2, W2, b2, out, S);
}

// Round 8
// 358.534 us; speedup vs baseline: 2.9887x; 2.9887x over previous
//
#include <hip/hip_runtime.h>
#include <stdint.h>

#define NN 8192
#define IN_DIM 32
#define HID_DIM 64
#define OUT_DIM 16

typedef __attribute__((ext_vector_type(8))) short short8;
typedef __attribute__((ext_vector_type(4))) float f32x4;

// fp32 -> bf16 bits, round-to-nearest-even
__device__ __forceinline__ short f2bf_bits(float x){
  uint32_t u = __builtin_bit_cast(uint32_t, x);
  u += 0x7FFFu + ((u >> 16) & 1u);
  return (short)(u >> 16);
}

__device__ __forceinline__ short8 cvt8(f32x4 lo, f32x4 hi){
  short8 r;
  r[0]=f2bf_bits(lo[0]); r[1]=f2bf_bits(lo[1]); r[2]=f2bf_bits(lo[2]); r[3]=f2bf_bits(lo[3]);
  r[4]=f2bf_bits(hi[0]); r[5]=f2bf_bits(hi[1]); r[6]=f2bf_bits(hi[2]); r[7]=f2bf_bits(hi[3]);
  return r;
}

// Kernel 0: Gt[c][r] = bf16( (X @ W1)[r][c] )   [64][8192]
__global__ __launch_bounds__(256) void k_g(const float* __restrict__ X, const float* __restrict__ W1,
                                           short* __restrict__ Gt){
  const int b    = blockIdx.x;
  const int rb   = (b & 127) * 64;
  const int cg   = b >> 7;
  const int lane = threadIdx.x & 63;
  const int c    = cg * 4 + (threadIdx.x >> 6);
  const int r    = rb + lane;
  const float* xr = X + (size_t)r * IN_DIM;
  float acc = 0.f;
  #pragma unroll
  for (int k = 0; k < IN_DIM; ++k)
    acc += xr[k] * W1[(size_t)k * HID_DIM + c];
  Gt[(size_t)c * NN + r] = f2bf_bits(acc);
}

// mm_sw: single-wave blocks (no __syncthreads -> no vmcnt(0) drains).
// Block = 1 wave, 16 rows of ONE adj matrix (z). K-group = 64 cols (4 KB via
// 4x global_load_lds, 256 B/row). 3-deep LDS ring (12 KB). B double-buffered
// in NAMED register arrays bA/bB with a manually 2x-unrolled loop so every
// index is compile-time (R7's runtime-indexed bf[] went to scratch: rule #20).
// Pacing: asm vmcnt(16) = stage(t+1)[4] + loadB(t+1)[8] + stage(t+2)[4] in
// flight; never drains. Granule-XOR at the GLOBAL source, LDS linear (m173).
template<int REV>
__global__ __launch_bounds__(64, 3) void mm_sw(const float* __restrict__ adj1, const float* __restrict__ adj2,
                                               const short* __restrict__ Bt,
                                               float* __restrict__ P1, float* __restrict__ P2, int klen){
  __shared__ __align__(16) float sA[3][16 * 64];      // 12 KB ring
  const int l     = threadIdx.x;                      // 0..63
  const int strip = REV ? ((int)gridDim.x - 1 - (int)blockIdx.x) : (int)blockIdx.x;
  const int ks    = REV ? ((int)gridDim.y - 1 - (int)blockIdx.y) : (int)blockIdx.y;
  const int z     = REV ? (1 - (int)blockIdx.z) : (int)blockIdx.z;
  const float* __restrict__ adj = z ? adj2 : adj1;
  const int k0    = ks * klen;
  const int ngrp  = klen >> 6;                        // 32 at S=4
  const int rl    = l & 15;                           // MFMA row / B col / stage granule
  const int qh    = l >> 4;                           // k-quad / stage row-in-quad
  const size_t rowb = (size_t)strip * 16 * NN;

  auto stage = [&](int t){
    if (t >= ngrp) return;
    const int g   = REV ? (ngrp - 1 - t) : t;
    const int buf = t % 3;
    const size_t colb = (size_t)(k0 + g * 64);
    #pragma unroll
    for (int p = 0; p < 4; ++p){
      const int row = p * 4 + qh;                     // 0..15, uniform per wave-instr
      const int sg  = rl ^ row;                       // swizzled source granule (16B)
      const float* s = adj + rowb + (size_t)row * NN + colb + sg * 4;
      __builtin_amdgcn_global_load_lds(
          (const __attribute__((address_space(1))) void*)s,
          (__attribute__((address_space(3))) void*)&sA[buf][p * 256 + l * 4], 16, 0, 0);
    }
  };

  auto loadB = [&](int t, short8 (&d)[2][4]){
    if (t >= ngrp) return;
    const int g = REV ? (ngrp - 1 - t) : t;
    const size_t bk = (size_t)(k0 + g * 64) + qh * 8;
    #pragma unroll
    for (int j = 0; j < 2; ++j)
      #pragma unroll
      for (int f = 0; f < 4; ++f)
        d[j][f] = *(const short8*)(Bt + (size_t)(f * 16 + rl) * NN + bk + j * 32);
  };

  f32x4 acc[4] = {{0,0,0,0},{0,0,0,0},{0,0,0,0},{0,0,0,0}};

  auto compute = [&](int t, const short8 (&b)[2][4]){
    const float* sa = &sA[t % 3][0];
    #pragma unroll
    for (int j = 0; j < 2; ++j){
      const int g0 = j * 8 + qh * 2;
      f32x4 lo = *(const f32x4*)(sa + rl * 64 + (((g0    ) ^ rl) << 2));
      f32x4 hi = *(const f32x4*)(sa + rl * 64 + (((g0 + 1) ^ rl) << 2));
      short8 fa = cvt8(lo, hi);
      #pragma unroll
      for (int f = 0; f < 4; ++f)
        acc[f] = __builtin_amdgcn_mfma_f32_16x16x32_bf16(fa, b[j][f], acc[f], 0, 0, 0);
    }
  };

  short8 bA[2][4], bB[2][4];

  // prologue: B(0) oldest, then stages 0,1
  loadB(0, bA);
  stage(0); stage(1);

  #pragma unroll 1
  for (int t = 0; t < ngrp; t += 2){
    // half 1: compute(t) from bA, prefetch B(t+1)->bB, stage(t+2)
    loadB(t + 1, bB);
    stage(t + 2);
    asm volatile("s_waitcnt vmcnt(16)" ::: "memory");
    __builtin_amdgcn_sched_barrier(0);
    compute(t, bA);
    // half 2: compute(t+1) from bB, prefetch B(t+2)->bA, stage(t+3)
    loadB(t + 2, bA);
    stage(t + 3);
    asm volatile("s_waitcnt vmcnt(16)" ::: "memory");
    __builtin_amdgcn_sched_barrier(0);
    compute(t + 1, bB);
  }

  // D layout: col = lane&15, row = (lane>>4)*4 + reg
  const int orow = strip * 16 + qh * 4;
  float* P = z ? P2 : P1;
  float* p = P + ((size_t)ks * NN + orow) * HID_DIM + rl;
  #pragma unroll
  for (int r = 0; r < 4; ++r){
    #pragma unroll
    for (int f = 0; f < 4; ++f)
      p[(size_t)r * HID_DIM + f * 16] = acc[f][r];
  }
}

// l1_combine: H1t[c][r] = bf16( relu(SY1+b1) + relu(SY2+b1) ), LDS transpose
__global__ __launch_bounds__(256) void l1_combine(const float* __restrict__ Y1p, const float* __restrict__ Y2p,
                                                  const float* __restrict__ b1,
                                                  short* __restrict__ H1t, int S){
  __shared__ float sH[64][65];
  const int tid = threadIdx.x, lane = tid & 63, wave = tid >> 6;
  const int rb = blockIdx.x * 64;
  const float bc = b1[lane];
  #pragma unroll 4
  for (int rq = 0; rq < 16; ++rq){
    const int r = rq * 4 + wave;
    const int row = rb + r;
    float s1 = 0.f, s2 = 0.f;
    for (int sp = 0; sp < S; ++sp){
      s1 += Y1p[((size_t)sp * NN + row) * HID_DIM + lane];
      s2 += Y2p[((size_t)sp * NN + row) * HID_DIM + lane];
    }
    sH[r][lane] = fmaxf(s1 + bc, 0.f) + fmaxf(s2 + bc, 0.f);
  }
  __syncthreads();
  #pragma unroll 4
  for (int i = 0; i < 16; ++i){
    const int c = wave * 16 + i;
    H1t[(size_t)c * NN + rb + lane] = f2bf_bits(sH[lane][c]);
  }
}

// l2_combine: out[row][c] = relu(Z1@W2+b2) + relu(Z2@W2+b2)
__global__ __launch_bounds__(256) void l2_combine(const float* __restrict__ Z1p, const float* __restrict__ Z2p,
                                                  const float* __restrict__ W2, const float* __restrict__ b2,
                                                  float* __restrict__ out, int S){
  __shared__ float sW[HID_DIM * OUT_DIM];
  __shared__ float sb[OUT_DIM];
  __shared__ float sz[4][2][HID_DIM];
  const int tid = threadIdx.x;
  for (int i = tid; i < HID_DIM * OUT_DIM; i += 256) sW[i] = W2[i];
  if (tid < OUT_DIM) sb[tid] = b2[tid];
  const int sub = tid >> 6, t = tid & 63;
  const int row = blockIdx.x * 4 + sub;
  float s1 = 0.f, s2 = 0.f;
  for (int sp = 0; sp < S; ++sp){
    s1 += Z1p[((size_t)sp * NN + row) * HID_DIM + t];
    s2 += Z2p[((size_t)sp * NN + row) * HID_DIM + t];
  }
  sz[sub][0][t] = s1;
  sz[sub][1][t] = s2;
  __syncthreads();
  if (t < OUT_DIM){
    float a = sb[t], b = sb[t];
    #pragma unroll
    for (int k = 0; k < HID_DIM; ++k){
      a += sz[sub][0][k] * sW[k * OUT_DIM + t];
      b += sz[sub][1][k] * sW[k * OUT_DIM + t];
    }
    out[(size_t)row * OUT_DIM + t] = fmaxf(a, 0.f) + fmaxf(b, 0.f);
  }
}

extern "C" void kernel_launch(void* const* d_in, const int* in_sizes, int n_in,
                              void* d_out, int out_size, void* d_ws, size_t ws_size,
                              hipStream_t stream){
  const float* adj1 = (const float*)d_in[0];
  const float* adj2 = (const float*)d_in[1];
  const float* X    = (const float*)d_in[2];
  const float* W1   = (const float*)d_in[3];
  const float* b1   = (const float*)d_in[4];
  const float* W2   = (const float*)d_in[5];
  const float* b2   = (const float*)d_in[6];
  float* out = (float*)d_out;

  char* ws = (char*)d_ws;
  short* Gt  = (short*)ws;                           // 64*8192*2 = 1 MB
  short* H1t = (short*)(ws + (size_t)1024 * 1024);   // 1 MB
  const size_t off = (size_t)2 * 1024 * 1024;

  int S = 4;
  while (S > 1 && off + (size_t)S * 4 * 1024 * 1024 > ws_size) S >>= 1;
  float* P1 = (float*)(ws + off);
  float* P2 = P1 + (size_t)S * NN * HID_DIM;
  const int klen = NN / S;

  k_g        <<<dim3(2048),          dim3(256), 0, stream>>>(X, W1, Gt);
  mm_sw<0>   <<<dim3(NN / 16, S, 2), dim3(64),  0, stream>>>(adj1, adj2, Gt, P1, P2, klen);
  l1_combine <<<dim3(NN / 64),       dim3(256), 0, stream>>>(P1, P2, b1, H1t, S);
  mm_sw<1>   <<<dim3(NN / 16, S, 2), dim3(64),  0, stream>>>(adj1, adj2, H1t, P1, P2, klen);
  l2_combine <<<dim3(NN / 4),        dim3(256), 0, stream>>>(P1, P2, W2, b2, out, S);
}

// Round 9
// 317.875 us; speedup vs baseline: 3.3710x; 1.1279x over previous
//
#include <hip/hip_runtime.h>
#include <stdint.h>

#define NN 8192
#define IN_DIM 32
#define HID_DIM 64
#define OUT_DIM 16

typedef __attribute__((ext_vector_type(8))) short short8;
typedef __attribute__((ext_vector_type(4))) float f32x4;

// fp32 -> bf16 bits, round-to-nearest-even
__device__ __forceinline__ short f2bf_bits(float x){
  uint32_t u = __builtin_bit_cast(uint32_t, x);
  u += 0x7FFFu + ((u >> 16) & 1u);
  return (short)(u >> 16);
}

__device__ __forceinline__ short8 cvt8(f32x4 lo, f32x4 hi){
  short8 r;
  r[0]=f2bf_bits(lo[0]); r[1]=f2bf_bits(lo[1]); r[2]=f2bf_bits(lo[2]); r[3]=f2bf_bits(lo[3]);
  r[4]=f2bf_bits(hi[0]); r[5]=f2bf_bits(hi[1]); r[6]=f2bf_bits(hi[2]); r[7]=f2bf_bits(hi[3]);
  return r;
}

// Kernel 0: Gt[c][r] = bf16( (X @ W1)[r][c] )   [64][8192]
__global__ __launch_bounds__(256) void k_g(const float* __restrict__ X, const float* __restrict__ W1,
                                           short* __restrict__ Gt){
  const int b    = blockIdx.x;
  const int rb   = (b & 127) * 64;
  const int cg   = b >> 7;
  const int lane = threadIdx.x & 63;
  const int c    = cg * 4 + (threadIdx.x >> 6);
  const int r    = rb + lane;
  const float* xr = X + (size_t)r * IN_DIM;
  float acc = 0.f;
  #pragma unroll
  for (int k = 0; k < IN_DIM; ++k)
    acc += xr[k] * W1[(size_t)k * HID_DIM + c];
  Gt[(size_t)c * NN + r] = f2bf_bits(acc);
}

// mm64: single-wave block owns 64 rows of ONE adj matrix (z) -> B fragments
// reused across 4 m-frags (B:A bytes 1:2 instead of 2:1; R8 spent 2/3 of the
// per-CU delivery ceiling on B). K-group = 64 cols: A 16KB via 16x
// global_load_lds (1KB linear each), B 8KB into named bA/bB register buffers.
// Ring-2 LDS (32KB -> 5 blocks/CU), uniform depth-2 FIFO, asm vmcnt(24)
// (= next group's 24 ops in flight; never drains). No __syncthreads anywhere.
// Granule-XOR (g ^ (row&15)) applied at the GLOBAL source, LDS linear (m173).
template<int REV>
__global__ __launch_bounds__(64, 2) void mm64(const float* __restrict__ adj1, const float* __restrict__ adj2,
                                              const short* __restrict__ Bt,
                                              float* __restrict__ P1, float* __restrict__ P2, int klen){
  __shared__ __align__(16) float sA[2][64 * 64];      // 2 x 16KB ring
  const int l     = threadIdx.x;                      // 0..63
  const int strip = REV ? ((int)gridDim.x - 1 - (int)blockIdx.x) : (int)blockIdx.x;
  const int ks    = REV ? ((int)gridDim.y - 1 - (int)blockIdx.y) : (int)blockIdx.y;
  const int z     = REV ? (1 - (int)blockIdx.z) : (int)blockIdx.z;
  const float* __restrict__ adj = z ? adj2 : adj1;
  const int k0    = ks * klen;
  const int ngrp  = klen >> 6;                        // 16 at S=8 (even)
  const int rl    = l & 15;                           // MFMA row / B col / granule
  const int qh    = l >> 4;                           // k-quad / stage row-in-4
  const size_t rowb = (size_t)strip * 64 * NN;

  auto stage = [&](int t){
    if (t >= ngrp) return;
    const int g   = REV ? (ngrp - 1 - t) : t;
    const int buf = t & 1;
    const size_t colb = (size_t)(k0 + g * 64);
    #pragma unroll
    for (int p = 0; p < 16; ++p){
      const int row = p * 4 + qh;                     // 0..63, uniform per wave-instr
      const int sg  = rl ^ (row & 15);                // swizzled source granule (16B)
      const float* s = adj + rowb + (size_t)row * NN + colb + sg * 4;
      __builtin_amdgcn_global_load_lds(
          (const __attribute__((address_space(1))) void*)s,
          (__attribute__((address_space(3))) void*)&sA[buf][p * 256 + l * 4], 16, 0, 0);
    }
  };

  auto loadB = [&](int t, short8 (&d)[2][4]){
    if (t >= ngrp) return;
    const int g = REV ? (ngrp - 1 - t) : t;
    const size_t bk = (size_t)(k0 + g * 64) + qh * 8;
    #pragma unroll
    for (int j = 0; j < 2; ++j)
      #pragma unroll
      for (int f = 0; f < 4; ++f)
        d[j][f] = *(const short8*)(Bt + (size_t)(f * 16 + rl) * NN + bk + j * 32);
  };

  f32x4 acc[4][4];
  #pragma unroll
  for (int mi = 0; mi < 4; ++mi)
    #pragma unroll
    for (int f = 0; f < 4; ++f)
      acc[mi][f] = f32x4{0.f,0.f,0.f,0.f};

  auto compute = [&](int t, const short8 (&b)[2][4]){
    const float* sa = &sA[t & 1][0];
    #pragma unroll
    for (int j = 0; j < 2; ++j){
      const int g0 = j * 8 + qh * 2;
      #pragma unroll
      for (int mi = 0; mi < 4; ++mi){
        const int r = mi * 16 + rl;
        f32x4 lo = *(const f32x4*)(sa + r * 64 + (((g0    ) ^ rl) << 2));
        f32x4 hi = *(const f32x4*)(sa + r * 64 + (((g0 + 1) ^ rl) << 2));
        short8 fa = cvt8(lo, hi);
        #pragma unroll
        for (int f = 0; f < 4; ++f)
          acc[mi][f] = __builtin_amdgcn_mfma_f32_16x16x32_bf16(fa, b[j][f], acc[mi][f], 0, 0, 0);
      }
    }
  };

  short8 bA[2][4], bB[2][4];

  loadB(0, bA);
  stage(0);

  #pragma unroll 1
  for (int t = 0; t < ngrp; t += 2){
    loadB(t + 1, bB);
    stage(t + 1);
    asm volatile("s_waitcnt vmcnt(24)" ::: "memory");
    __builtin_amdgcn_sched_barrier(0);
    compute(t, bA);
    loadB(t + 2, bA);
    stage(t + 2);
    asm volatile("s_waitcnt vmcnt(24)" ::: "memory");
    __builtin_amdgcn_sched_barrier(0);
    compute(t + 1, bB);
  }

  // D layout per 16x16 frag: col = lane&15, row = (lane>>4)*4 + reg
  float* P = z ? P2 : P1;
  #pragma unroll
  for (int mi = 0; mi < 4; ++mi){
    const int orow = strip * 64 + mi * 16 + qh * 4;
    float* p = P + ((size_t)ks * NN + orow) * HID_DIM + rl;
    #pragma unroll
    for (int r = 0; r < 4; ++r){
      #pragma unroll
      for (int f = 0; f < 4; ++f)
        p[(size_t)r * HID_DIM + f * 16] = acc[mi][f][r];
    }
  }
}

// l1_combine: H1t[c][r] = bf16( relu(SY1+b1) + relu(SY2+b1) ), LDS transpose
__global__ __launch_bounds__(256) void l1_combine(const float* __restrict__ Y1p, const float* __restrict__ Y2p,
                                                  const float* __restrict__ b1,
                                                  short* __restrict__ H1t, int S){
  __shared__ float sH[64][65];
  const int tid = threadIdx.x, lane = tid & 63, wave = tid >> 6;
  const int rb = blockIdx.x * 64;
  const float bc = b1[lane];
  #pragma unroll 4
  for (int rq = 0; rq < 16; ++rq){
    const int r = rq * 4 + wave;
    const int row = rb + r;
    float s1 = 0.f, s2 = 0.f;
    for (int sp = 0; sp < S; ++sp){
      s1 += Y1p[((size_t)sp * NN + row) * HID_DIM + lane];
      s2 += Y2p[((size_t)sp * NN + row) * HID_DIM + lane];
    }
    sH[r][lane] = fmaxf(s1 + bc, 0.f) + fmaxf(s2 + bc, 0.f);
  }
  __syncthreads();
  #pragma unroll 4
  for (int i = 0; i < 16; ++i){
    const int c = wave * 16 + i;
    H1t[(size_t)c * NN + rb + lane] = f2bf_bits(sH[lane][c]);
  }
}

// l2_combine: out[row][c] = relu(Z1@W2+b2) + relu(Z2@W2+b2)
__global__ __launch_bounds__(256) void l2_combine(const float* __restrict__ Z1p, const float* __restrict__ Z2p,
                                                  const float* __restrict__ W2, const float* __restrict__ b2,
                                                  float* __restrict__ out, int S){
  __shared__ float sW[HID_DIM * OUT_DIM];
  __shared__ float sb[OUT_DIM];
  __shared__ float sz[4][2][HID_DIM];
  const int tid = threadIdx.x;
  for (int i = tid; i < HID_DIM * OUT_DIM; i += 256) sW[i] = W2[i];
  if (tid < OUT_DIM) sb[tid] = b2[tid];
  const int sub = tid >> 6, t = tid & 63;
  const int row = blockIdx.x * 4 + sub;
  float s1 = 0.f, s2 = 0.f;
  for (int sp = 0; sp < S; ++sp){
    s1 += Z1p[((size_t)sp * NN + row) * HID_DIM + t];
    s2 += Z2p[((size_t)sp * NN + row) * HID_DIM + t];
  }
  sz[sub][0][t] = s1;
  sz[sub][1][t] = s2;
  __syncthreads();
  if (t < OUT_DIM){
    float a = sb[t], b = sb[t];
    #pragma unroll
    for (int k = 0; k < HID_DIM; ++k){
      a += sz[sub][0][k] * sW[k * OUT_DIM + t];
      b += sz[sub][1][k] * sW[k * OUT_DIM + t];
    }
    out[(size_t)row * OUT_DIM + t] = fmaxf(a, 0.f) + fmaxf(b, 0.f);
  }
}

extern "C" void kernel_launch(void* const* d_in, const int* in_sizes, int n_in,
                              void* d_out, int out_size, void* d_ws, size_t ws_size,
                              hipStream_t stream){
  const float* adj1 = (const float*)d_in[0];
  const float* adj2 = (const float*)d_in[1];
  const float* X    = (const float*)d_in[2];
  const float* W1   = (const float*)d_in[3];
  const float* b1   = (const float*)d_in[4];
  const float* W2   = (const float*)d_in[5];
  const float* b2   = (const float*)d_in[6];
  float* out = (float*)d_out;

  char* ws = (char*)d_ws;
  short* Gt  = (short*)ws;                           // 64*8192*2 = 1 MB
  short* H1t = (short*)(ws + (size_t)1024 * 1024);   // 1 MB
  const size_t off = (size_t)2 * 1024 * 1024;

  // S=8: 2048 mm blocks (5/CU resident -> decent tail), P1+P2 = 32 MB.
  int S = 8;
  while (S > 1 && off + (size_t)S * 4 * 1024 * 1024 > ws_size) S >>= 1;
  float* P1 = (float*)(ws + off);
  float* P2 = P1 + (size_t)S * NN * HID_DIM;
  const int klen = NN / S;

  k_g        <<<dim3(2048),          dim3(256), 0, stream>>>(X, W1, Gt);
  mm64<0>    <<<dim3(NN / 64, S, 2), dim3(64),  0, stream>>>(adj1, adj2, Gt, P1, P2, klen);
  l1_combine <<<dim3(NN / 64),       dim3(256), 0, stream>>>(P1, P2, b1, H1t, S);
  mm64<1>    <<<dim3(NN / 64, S, 2), dim3(64),  0, stream>>>(adj1, adj2, H1t, P1, P2, klen);
  l2_combine <<<dim3(NN / 4),        dim3(256), 0, stream>>>(P1, P2, W2, b2, out, S);
}

// Round 10
// 269.237 us; speedup vs baseline: 3.9799x; 1.1807x over previous
//
#include <hip/hip_runtime.h>
#include <stdint.h>

#define NN 8192
#define IN_DIM 32
#define HID_DIM 64
#define OUT_DIM 16

typedef __attribute__((ext_vector_type(8))) short short8;
typedef __attribute__((ext_vector_type(4))) float f32x4;

// fp32 -> bf16 bits, round-to-nearest-even
__device__ __forceinline__ short f2bf_bits(float x){
  uint32_t u = __builtin_bit_cast(uint32_t, x);
  u += 0x7FFFu + ((u >> 16) & 1u);
  return (short)(u >> 16);
}

__device__ __forceinline__ short8 cvt8(f32x4 lo, f32x4 hi){
  short8 r;
  r[0]=f2bf_bits(lo[0]); r[1]=f2bf_bits(lo[1]); r[2]=f2bf_bits(lo[2]); r[3]=f2bf_bits(lo[3]);
  r[4]=f2bf_bits(hi[0]); r[5]=f2bf_bits(hi[1]); r[6]=f2bf_bits(hi[2]); r[7]=f2bf_bits(hi[3]);
  return r;
}

// Kernel 0: Gt[c][r] = bf16( (X @ W1)[r][c] )   [64][8192]
__global__ __launch_bounds__(256) void k_g(const float* __restrict__ X, const float* __restrict__ W1,
                                           short* __restrict__ Gt){
  const int b    = blockIdx.x;
  const int rb   = (b & 127) * 64;
  const int cg   = b >> 7;
  const int lane = threadIdx.x & 63;
  const int c    = cg * 4 + (threadIdx.x >> 6);
  const int r    = rb + lane;
  const float* xr = X + (size_t)r * IN_DIM;
  float acc = 0.f;
  #pragma unroll
  for (int k = 0; k < IN_DIM; ++k)
    acc += xr[k] * W1[(size_t)k * HID_DIM + c];
  Gt[(size_t)c * NN + r] = f2bf_bits(acc);
}

// mm64: R9 structure verbatim (single-wave block, 64 rows of one adj matrix,
// K-group=64 cols, ring-2 LDS via global_load_lds, named bA/bB B-buffers,
// counted vmcnt(24), no __syncthreads) + ONE change: per-block K-phase skew.
// Without skew all concurrent blocks read the SAME 256B column window (row
// stride 32KB only touches addr bits >=15) -> HBM channel camping at ~1.4TB/s.
// phase=(strip+8z)&15 spreads blocks over 16 windows x 8 ks. REV = exact
// temporal mirror of FWD's skewed walk (preserves L3 ping-pong).
template<int REV>
__global__ __launch_bounds__(64, 2) void mm64(const float* __restrict__ adj1, const float* __restrict__ adj2,
                                              const short* __restrict__ Bt,
                                              float* __restrict__ P1, float* __restrict__ P2, int klen){
  __shared__ __align__(16) float sA[2][64 * 64];      // 2 x 16KB ring
  const int l     = threadIdx.x;                      // 0..63
  const int strip = REV ? ((int)gridDim.x - 1 - (int)blockIdx.x) : (int)blockIdx.x;
  const int ks    = REV ? ((int)gridDim.y - 1 - (int)blockIdx.y) : (int)blockIdx.y;
  const int z     = REV ? (1 - (int)blockIdx.z) : (int)blockIdx.z;
  const float* __restrict__ adj = z ? adj2 : adj1;
  const int k0    = ks * klen;
  const int ngrp  = klen >> 6;                        // 16 at S=8
  const int phase = (strip + (z << 3)) & (ngrp - 1);  // channel-spread skew
  const int rl    = l & 15;                           // MFMA row / B col / granule
  const int qh    = l >> 4;                           // k-quad / stage row-in-4
  const size_t rowb = (size_t)strip * 64 * NN;

  // time t -> column group. FWD: (phase+t) mod n. REV: FWD's walk reversed.
  auto gmap = [&](int t){
    const int tg = REV ? (phase + ngrp - 1 - t) : (phase + t);
    return tg & (ngrp - 1);
  };

  auto stage = [&](int t){
    if (t >= ngrp) return;
    const int g   = gmap(t);
    const int buf = t & 1;
    const size_t colb = (size_t)(k0 + g * 64);
    #pragma unroll
    for (int p = 0; p < 16; ++p){
      const int row = p * 4 + qh;                     // 0..63, uniform per wave-instr
      const int sg  = rl ^ (row & 15);                // swizzled source granule (16B)
      const float* s = adj + rowb + (size_t)row * NN + colb + sg * 4;
      __builtin_amdgcn_global_load_lds(
          (const __attribute__((address_space(1))) void*)s,
          (__attribute__((address_space(3))) void*)&sA[buf][p * 256 + l * 4], 16, 0, 0);
    }
  };

  auto loadB = [&](int t, short8 (&d)[2][4]){
    if (t >= ngrp) return;
    const int g = gmap(t);
    const size_t bk = (size_t)(k0 + g * 64) + qh * 8;
    #pragma unroll
    for (int j = 0; j < 2; ++j)
      #pragma unroll
      for (int f = 0; f < 4; ++f)
        d[j][f] = *(const short8*)(Bt + (size_t)(f * 16 + rl) * NN + bk + j * 32);
  };

  f32x4 acc[4][4];
  #pragma unroll
  for (int mi = 0; mi < 4; ++mi)
    #pragma unroll
    for (int f = 0; f < 4; ++f)
      acc[mi][f] = f32x4{0.f,0.f,0.f,0.f};

  auto compute = [&](int t, const short8 (&b)[2][4]){
    const float* sa = &sA[t & 1][0];
    #pragma unroll
    for (int j = 0; j < 2; ++j){
      const int g0 = j * 8 + qh * 2;
      #pragma unroll
      for (int mi = 0; mi < 4; ++mi){
        const int r = mi * 16 + rl;
        f32x4 lo = *(const f32x4*)(sa + r * 64 + (((g0    ) ^ rl) << 2));
        f32x4 hi = *(const f32x4*)(sa + r * 64 + (((g0 + 1) ^ rl) << 2));
        short8 fa = cvt8(lo, hi);
        #pragma unroll
        for (int f = 0; f < 4; ++f)
          acc[mi][f] = __builtin_amdgcn_mfma_f32_16x16x32_bf16(fa, b[j][f], acc[mi][f], 0, 0, 0);
      }
    }
  };

  short8 bA[2][4], bB[2][4];

  loadB(0, bA);
  stage(0);

  #pragma unroll 1
  for (int t = 0; t < ngrp; t += 2){
    loadB(t + 1, bB);
    stage(t + 1);
    asm volatile("s_waitcnt vmcnt(24)" ::: "memory");
    __builtin_amdgcn_sched_barrier(0);
    compute(t, bA);
    loadB(t + 2, bA);
    stage(t + 2);
    asm volatile("s_waitcnt vmcnt(24)" ::: "memory");
    __builtin_amdgcn_sched_barrier(0);
    compute(t + 1, bB);
  }

  // D layout per 16x16 frag: col = lane&15, row = (lane>>4)*4 + reg
  float* P = z ? P2 : P1;
  #pragma unroll
  for (int mi = 0; mi < 4; ++mi){
    const int orow = strip * 64 + mi * 16 + qh * 4;
    float* p = P + ((size_t)ks * NN + orow) * HID_DIM + rl;
    #pragma unroll
    for (int r = 0; r < 4; ++r){
      #pragma unroll
      for (int f = 0; f < 4; ++f)
        p[(size_t)r * HID_DIM + f * 16] = acc[mi][f][r];
    }
  }
}

// l1_combine: H1t[c][r] = bf16( relu(SY1+b1) + relu(SY2+b1) ), LDS transpose
__global__ __launch_bounds__(256) void l1_combine(const float* __restrict__ Y1p, const float* __restrict__ Y2p,
                                                  const float* __restrict__ b1,
                                                  short* __restrict__ H1t, int S){
  __shared__ float sH[64][65];
  const int tid = threadIdx.x, lane = tid & 63, wave = tid >> 6;
  const int rb = blockIdx.x * 64;
  const float bc = b1[lane];
  #pragma unroll 4
  for (int rq = 0; rq < 16; ++rq){
    const int r = rq * 4 + wave;
    const int row = rb + r;
    float s1 = 0.f, s2 = 0.f;
    for (int sp = 0; sp < S; ++sp){
      s1 += Y1p[((size_t)sp * NN + row) * HID_DIM + lane];
      s2 += Y2p[((size_t)sp * NN + row) * HID_DIM + lane];
    }
    sH[r][lane] = fmaxf(s1 + bc, 0.f) + fmaxf(s2 + bc, 0.f);
  }
  __syncthreads();
  #pragma unroll 4
  for (int i = 0; i < 16; ++i){
    const int c = wave * 16 + i;
    H1t[(size_t)c * NN + rb + lane] = f2bf_bits(sH[lane][c]);
  }
}

// l2_combine: out[row][c] = relu(Z1@W2+b2) + relu(Z2@W2+b2)
__global__ __launch_bounds__(256) void l2_combine(const float* __restrict__ Z1p, const float* __restrict__ Z2p,
                                                  const float* __restrict__ W2, const float* __restrict__ b2,
                                                  float* __restrict__ out, int S){
  __shared__ float sW[HID_DIM * OUT_DIM];
  __shared__ float sb[OUT_DIM];
  __shared__ float sz[4][2][HID_DIM];
  const int tid = threadIdx.x;
  for (int i = tid; i < HID_DIM * OUT_DIM; i += 256) sW[i] = W2[i];
  if (tid < OUT_DIM) sb[tid] = b2[tid];
  const int sub = tid >> 6, t = tid & 63;
  const int row = blockIdx.x * 4 + sub;
  float s1 = 0.f, s2 = 0.f;
  for (int sp = 0; sp < S; ++sp){
    s1 += Z1p[((size_t)sp * NN + row) * HID_DIM + t];
    s2 += Z2p[((size_t)sp * NN + row) * HID_DIM + t];
  }
  sz[sub][0][t] = s1;
  sz[sub][1][t] = s2;
  __syncthreads();
  if (t < OUT_DIM){
    float a = sb[t], b = sb[t];
    #pragma unroll
    for (int k = 0; k < HID_DIM; ++k){
      a += sz[sub][0][k] * sW[k * OUT_DIM + t];
      b += sz[sub][1][k] * sW[k * OUT_DIM + t];
    }
    out[(size_t)row * OUT_DIM + t] = fmaxf(a, 0.f) + fmaxf(b, 0.f);
  }
}

extern "C" void kernel_launch(void* const* d_in, const int* in_sizes, int n_in,
                              void* d_out, int out_size, void* d_ws, size_t ws_size,
                              hipStream_t stream){
  const float* adj1 = (const float*)d_in[0];
  const float* adj2 = (const float*)d_in[1];
  const float* X    = (const float*)d_in[2];
  const float* W1   = (const float*)d_in[3];
  const float* b1   = (const float*)d_in[4];
  const float* W2   = (const float*)d_in[5];
  const float* b2   = (const float*)d_in[6];
  float* out = (float*)d_out;

  char* ws = (char*)d_ws;
  short* Gt  = (short*)ws;                           // 64*8192*2 = 1 MB
  short* H1t = (short*)(ws + (size_t)1024 * 1024);   // 1 MB
  const size_t off = (size_t)2 * 1024 * 1024;

  int S = 8;
  while (S > 1 && off + (size_t)S * 4 * 1024 * 1024 > ws_size) S >>= 1;
  float* P1 = (float*)(ws + off);
  float* P2 = P1 + (size_t)S * NN * HID_DIM;
  const int klen = NN / S;

  k_g        <<<dim3(2048),          dim3(256), 0, stream>>>(X, W1, Gt);
  mm64<0>    <<<dim3(NN / 64, S, 2), dim3(64),  0, stream>>>(adj1, adj2, Gt, P1, P2, klen);
  l1_combine <<<dim3(NN / 64),       dim3(256), 0, stream>>>(P1, P2, b1, H1t, S);
  mm64<1>    <<<dim3(NN / 64, S, 2), dim3(64),  0, stream>>>(adj1, adj2, H1t, P1, P2, klen);
  l2_combine <<<dim3(NN / 4),        dim3(256), 0, stream>>>(P1, P2, W2, b2, out, S);
}

// Round 11
// 261.993 us; speedup vs baseline: 4.0900x; 1.0277x over previous
//
#include <hip/hip_runtime.h>
#include <stdint.h>

#define NN 8192
#define IN_DIM 32
#define HID_DIM 64
#define OUT_DIM 16

typedef __attribute__((ext_vector_type(8))) short short8;
typedef __attribute__((ext_vector_type(4))) float f32x4;

// fp32 -> bf16 bits, round-to-nearest-even
__device__ __forceinline__ short f2bf_bits(float x){
  uint32_t u = __builtin_bit_cast(uint32_t, x);
  u += 0x7FFFu + ((u >> 16) & 1u);
  return (short)(u >> 16);
}

__device__ __forceinline__ short8 cvt8(f32x4 lo, f32x4 hi){
  short8 r;
  r[0]=f2bf_bits(lo[0]); r[1]=f2bf_bits(lo[1]); r[2]=f2bf_bits(lo[2]); r[3]=f2bf_bits(lo[3]);
  r[4]=f2bf_bits(hi[0]); r[5]=f2bf_bits(hi[1]); r[6]=f2bf_bits(hi[2]); r[7]=f2bf_bits(hi[3]);
  return r;
}

// Kernel 0: Gt[c][r] = bf16( (X @ W1)[r][c] )   [64][8192]
__global__ __launch_bounds__(256) void k_g(const float* __restrict__ X, const float* __restrict__ W1,
                                           short* __restrict__ Gt){
  const int b    = blockIdx.x;
  const int rb   = (b & 127) * 64;
  const int cg   = b >> 7;
  const int lane = threadIdx.x & 63;
  const int c    = cg * 4 + (threadIdx.x >> 6);
  const int r    = rb + lane;
  const float* xr = X + (size_t)r * IN_DIM;
  float acc = 0.f;
  #pragma unroll
  for (int k = 0; k < IN_DIM; ++k)
    acc += xr[k] * W1[(size_t)k * HID_DIM + c];
  Gt[(size_t)c * NN + r] = f2bf_bits(acc);
}

// mm64r: R10 structure (single-wave block, 64 rows of one adj matrix, skewed
// K-walk, counted vmcnt, no barriers) with ONE change: staging via REGISTER
// loads + ds_write instead of global_load_lds. A/B test of the LDS-DMA path:
// every gload_lds variant pinned at 1.3-1.8 TB/s; plain-load kernels (R7
// scratch, m13 copy) hit 3.2-6.3 TB/s. K-group = 32 cols (128 B/row), 8x
// global_load_dwordx4 -> SA[8] (static idx) -> 8x ds_write_b128 swizzled,
// ring-2 LDS 16 KB. vmcnt ledger (in-order retirement): steady in-flight =
// SL[8]+BL[4]; waits alternate vmcnt(4)/vmcnt(8); explicit 2-group epilogue
// keeps counts exact at the tail (guarded no-ops would falsify them).
template<int REV>
__global__ __launch_bounds__(64, 2) void mm64r(const float* __restrict__ adj1, const float* __restrict__ adj2,
                                               const short* __restrict__ Bt,
                                               float* __restrict__ P1, float* __restrict__ P2, int klen){
  __shared__ __align__(16) float sA[2][64 * 32];      // 2 x 8 KB ring
  const int l     = threadIdx.x;                      // 0..63
  const int strip = REV ? ((int)gridDim.x - 1 - (int)blockIdx.x) : (int)blockIdx.x;
  const int ks    = REV ? ((int)gridDim.y - 1 - (int)blockIdx.y) : (int)blockIdx.y;
  const int z     = REV ? (1 - (int)blockIdx.z) : (int)blockIdx.z;
  const float* __restrict__ adj = z ? adj2 : adj1;
  const int k0    = ks * klen;
  const int ngrp  = klen >> 5;                        // 32 at S=8 (>=4, even)
  const int phase = (strip + (z << 3)) & (ngrp - 1);  // channel-spread skew
  const int rl    = l & 15;                           // MFMA row / B col
  const int qh    = l >> 4;                           // k-quad
  const int sr8   = l >> 3;                           // stage row-within-8
  const int sg    = (l & 7) ^ sr8;                    // static swizzled granule
  const size_t rowb = (size_t)strip * 64 * NN;

  auto gmap = [&](int t){
    const int tg = REV ? (phase + ngrp - 1 - t) : (phase + t);
    return tg & (ngrp - 1);
  };

  // stage-load group t into SA (8 x global_load_dwordx4, 128 B per row run)
  auto SL = [&](int t, f32x4 (&R)[8]){
    const int g = gmap(t);
    const float* base = adj + rowb + (size_t)(k0 + g * 32) + sg * 4;
    #pragma unroll
    for (int p = 0; p < 8; ++p)
      R[p] = *(const f32x4*)(base + (size_t)(p * 8 + sr8) * NN);
  };

  // ds_write SA -> LDS buf, slot (l&7) holds source granule sg = (l&7)^(row&7)
  auto DW = [&](const f32x4 (&R)[8], float* buf){
    float* dst = buf + (l & 7) * 4;
    #pragma unroll
    for (int p = 0; p < 8; ++p)
      *(f32x4*)(dst + (p * 8 + sr8) * 32) = R[p];
  };

  auto BL = [&](int t, short8 (&d)[4]){
    const int g = gmap(t);
    const size_t bk = (size_t)(k0 + g * 32) + qh * 8;
    #pragma unroll
    for (int f = 0; f < 4; ++f)
      d[f] = *(const short8*)(Bt + (size_t)(f * 16 + rl) * NN + bk);
  };

  f32x4 acc[4][4];
  #pragma unroll
  for (int mi = 0; mi < 4; ++mi)
    #pragma unroll
    for (int f = 0; f < 4; ++f)
      acc[mi][f] = f32x4{0.f,0.f,0.f,0.f};

  auto compute = [&](const float* sa, const short8 (&b)[4]){
    #pragma unroll
    for (int mi = 0; mi < 4; ++mi){
      const int row = mi * 16 + rl;
      f32x4 lo = *(const f32x4*)(sa + row * 32 + (((qh * 2    ) ^ (rl & 7)) << 2));
      f32x4 hi = *(const f32x4*)(sa + row * 32 + (((qh * 2 + 1) ^ (rl & 7)) << 2));
      short8 fa = cvt8(lo, hi);
      #pragma unroll
      for (int f = 0; f < 4; ++f)
        acc[mi][f] = __builtin_amdgcn_mfma_f32_16x16x32_bf16(fa, b[f], acc[mi][f], 0, 0, 0);
    }
  };

  f32x4 SA[8];
  short8 bA[4], bB[4];

  SL(0, SA); BL(0, bA);                               // in flight: SL[8]+BL[4]

  #pragma unroll 1
  for (int t = 0; t < ngrp - 2; t += 2){
    asm volatile("s_waitcnt vmcnt(4)" ::: "memory");  // SL(t) arrived (BL(t) remains)
    __builtin_amdgcn_sched_barrier(0);
    DW(SA, &sA[0][0]);
    SL(t + 1, SA);                                    // WAR on SA: lgkm auto-ordered
    asm volatile("s_waitcnt vmcnt(8)" ::: "memory");  // BL(t) arrived
    __builtin_amdgcn_sched_barrier(0);
    BL(t + 1, bB);
    compute(&sA[0][0], bA);
    asm volatile("s_waitcnt vmcnt(4)" ::: "memory");  // SL(t+1) arrived
    __builtin_amdgcn_sched_barrier(0);
    DW(SA, &sA[1][0]);
    SL(t + 2, SA);
    asm volatile("s_waitcnt vmcnt(8)" ::: "memory");  // BL(t+1) arrived
    __builtin_amdgcn_sched_barrier(0);
    BL(t + 2, bA);
    compute(&sA[1][0], bB);
  }
  // epilogue: groups ngrp-2, ngrp-1 (in flight: SL(ngrp-2)+BL(ngrp-2))
  asm volatile("s_waitcnt vmcnt(4)" ::: "memory");
  __builtin_amdgcn_sched_barrier(0);
  DW(SA, &sA[0][0]);
  SL(ngrp - 1, SA);
  asm volatile("s_waitcnt vmcnt(8)" ::: "memory");
  __builtin_amdgcn_sched_barrier(0);
  BL(ngrp - 1, bB);
  compute(&sA[0][0], bA);
  asm volatile("s_waitcnt vmcnt(4)" ::: "memory");    // SL(ngrp-1) arrived
  __builtin_amdgcn_sched_barrier(0);
  DW(SA, &sA[1][0]);
  asm volatile("s_waitcnt vmcnt(0)" ::: "memory");    // BL(ngrp-1) arrived
  __builtin_amdgcn_sched_barrier(0);
  compute(&sA[1][0], bB);

  // D layout per 16x16 frag: col = lane&15, row = (lane>>4)*4 + reg
  float* P = z ? P2 : P1;
  #pragma unroll
  for (int mi = 0; mi < 4; ++mi){
    const int orow = strip * 64 + mi * 16 + qh * 4;
    float* p = P + ((size_t)ks * NN + orow) * HID_DIM + rl;
    #pragma unroll
    for (int r = 0; r < 4; ++r){
      #pragma unroll
      for (int f = 0; f < 4; ++f)
        p[(size_t)r * HID_DIM + f * 16] = acc[mi][f][r];
    }
  }
}

// l1_combine: H1t[c][r] = bf16( relu(SY1+b1) + relu(SY2+b1) ), LDS transpose
__global__ __launch_bounds__(256) void l1_combine(const float* __restrict__ Y1p, const float* __restrict__ Y2p,
                                                  const float* __restrict__ b1,
                                                  short* __restrict__ H1t, int S){
  __shared__ float sH[64][65];
  const int tid = threadIdx.x, lane = tid & 63, wave = tid >> 6;
  const int rb = blockIdx.x * 64;
  const float bc = b1[lane];
  #pragma unroll 4
  for (int rq = 0; rq < 16; ++rq){
    const int r = rq * 4 + wave;
    const int row = rb + r;
    float s1 = 0.f, s2 = 0.f;
    for (int sp = 0; sp < S; ++sp){
      s1 += Y1p[((size_t)sp * NN + row) * HID_DIM + lane];
      s2 += Y2p[((size_t)sp * NN + row) * HID_DIM + lane];
    }
    sH[r][lane] = fmaxf(s1 + bc, 0.f) + fmaxf(s2 + bc, 0.f);
  }
  __syncthreads();
  #pragma unroll 4
  for (int i = 0; i < 16; ++i){
    const int c = wave * 16 + i;
    H1t[(size_t)c * NN + rb + lane] = f2bf_bits(sH[lane][c]);
  }
}

// l2_combine: out[row][c] = relu(Z1@W2+b2) + relu(Z2@W2+b2)
__global__ __launch_bounds__(256) void l2_combine(const float* __restrict__ Z1p, const float* __restrict__ Z2p,
                                                  const float* __restrict__ W2, const float* __restrict__ b2,
                                                  float* __restrict__ out, int S){
  __shared__ float sW[HID_DIM * OUT_DIM];
  __shared__ float sb[OUT_DIM];
  __shared__ float sz[4][2][HID_DIM];
  const int tid = threadIdx.x;
  for (int i = tid; i < HID_DIM * OUT_DIM; i += 256) sW[i] = W2[i];
  if (tid < OUT_DIM) sb[tid] = b2[tid];
  const int sub = tid >> 6, t = tid & 63;
  const int row = blockIdx.x * 4 + sub;
  float s1 = 0.f, s2 = 0.f;
  for (int sp = 0; sp < S; ++sp){
    s1 += Z1p[((size_t)sp * NN + row) * HID_DIM + t];
    s2 += Z2p[((size_t)sp * NN + row) * HID_DIM + t];
  }
  sz[sub][0][t] = s1;
  sz[sub][1][t] = s2;
  __syncthreads();
  if (t < OUT_DIM){
    float a = sb[t], b = sb[t];
    #pragma unroll
    for (int k = 0; k < HID_DIM; ++k){
      a += sz[sub][0][k] * sW[k * OUT_DIM + t];
      b += sz[sub][1][k] * sW[k * OUT_DIM + t];
    }
    out[(size_t)row * OUT_DIM + t] = fmaxf(a, 0.f) + fmaxf(b, 0.f);
  }
}

extern "C" void kernel_launch(void* const* d_in, const int* in_sizes, int n_in,
                              void* d_out, int out_size, void* d_ws, size_t ws_size,
                              hipStream_t stream){
  const float* adj1 = (const float*)d_in[0];
  const float* adj2 = (const float*)d_in[1];
  const float* X    = (const float*)d_in[2];
  const float* W1   = (const float*)d_in[3];
  const float* b1   = (const float*)d_in[4];
  const float* W2   = (const float*)d_in[5];
  const float* b2   = (const float*)d_in[6];
  float* out = (float*)d_out;

  char* ws = (char*)d_ws;
  short* Gt  = (short*)ws;                           // 64*8192*2 = 1 MB
  short* H1t = (short*)(ws + (size_t)1024 * 1024);   // 1 MB
  const size_t off = (size_t)2 * 1024 * 1024;

  int S = 8;
  while (S > 1 && off + (size_t)S * 4 * 1024 * 1024 > ws_size) S >>= 1;
  float* P1 = (float*)(ws + off);
  float* P2 = P1 + (size_t)S * NN * HID_DIM;
  const int klen = NN / S;

  k_g        <<<dim3(2048),          dim3(256), 0, stream>>>(X, W1, Gt);
  mm64r<0>   <<<dim3(NN / 64, S, 2), dim3(64),  0, stream>>>(adj1, adj2, Gt, P1, P2, klen);
  l1_combine <<<dim3(NN / 64),       dim3(256), 0, stream>>>(P1, P2, b1, H1t, S);
  mm64r<1>   <<<dim3(NN / 64, S, 2), dim3(64),  0, stream>>>(adj1, adj2, H1t, P1, P2, klen);
  l2_combine <<<dim3(NN / 4),        dim3(256), 0, stream>>>(P1, P2, W2, b2, out, S);
}